// Round 1
// 457.968 us; speedup vs baseline: 1.0803x; 1.0803x over previous
//
#include <hip/hip_runtime.h>
#include <hip/hip_bf16.h>

#define NN 50000
#define EE 800000
#define HIDD 128
#define NL 4
#define NC 10
#define BN_EPS 1e-5f

typedef __bf16 bf16x8 __attribute__((ext_vector_type(8)));
typedef float f32x4 __attribute__((ext_vector_type(4)));

__device__ __forceinline__ float bf_lo(unsigned int u) { return __uint_as_float(u << 16); }
__device__ __forceinline__ float bf_hi(unsigned int u) { return __uint_as_float(u & 0xFFFF0000u); }

__device__ __forceinline__ int edge_at(const void* ei, int i64, long long idx) {
    return i64 ? (int)((const long long*)ei)[idx] : ((const int*)ei)[idx];
}

__device__ __forceinline__ float flt_at(const void* p, int fp32, size_t idx) {
    return fp32 ? ((const float*)p)[idx] : (float)((const __hip_bfloat16*)p)[idx];
}

// ---------------- setup: detect flags + convert small arrays + pack B + zero scratch ----------------
// Blocks 0..319: pack B planes. Blocks 320..331: small-array convert. Blocks 332..347: zeroing.
// Each working block redundantly detects dtype flags from the first KBs (L2-hot); block 0 publishes.
__global__ __launch_bounds__(256) void k_setup(const void* h, const void* ei,
        const void* Wemb, const void* Ws,
        const void* bemb, const void* bs, const void* gam, const void* bet,
        const void* Wm, const void* bm,
        float* bemb_f, float* bs_f, float* gam_f, float* bet_f, float* Wm_f, float* bm_f,
        __bf16* Bhi, __bf16* Blo, int* counts, float* stats, int* flags) {
    int b = blockIdx.x, tid = threadIdx.x;
    if (b >= 332) {  // zero counts (50000 ints) + stats (4 layers x 8 reps x 256 floats)
        int idx = (b - 332) * 256 + tid;
        for (int j = idx; j < 12500; j += 4096) ((int4*)counts)[j] = make_int4(0, 0, 0, 0);
        for (int j = idx; j < 2048; j += 4096) ((int4*)stats)[j] = make_int4(0, 0, 0, 0);
        return;
    }
    __shared__ int wild, zeros;
    if (tid == 0) { wild = 0; zeros = 0; }
    __syncthreads();
    const unsigned short* hb = (const unsigned short*)h;
    int lw = 0;
    for (int i = tid; i < 4096; i += 256) {
        unsigned short u = hb[i];
        int e = (u >> 7) & 0xFF;
        if ((e >= 0x8F || e == 0) && (u & 0x7FFF) != 0) lw++;
    }
    if (lw) atomicAdd(&wild, lw);
    const int* ii = (const int*)ei;
    int lz = 0;
    for (int i = tid; i < 512; i += 256)
        if (ii[2 * i + 1] == 0) lz++;
    if (lz) atomicAdd(&zeros, lz);
    __syncthreads();
    int fp32 = (wild > 256) ? 1 : 0;
    int i64  = (zeros > 256) ? 1 : 0;
    if (b == 0 && tid == 0) { flags[0] = fp32; flags[1] = i64; }
    if (b < 320) {  // pack 5 weight matrices into MFMA B-fragment order, hi/lo planes
        int idx = b * 256 + tid;  // < 81920
        int m = idx >> 14, r = idx & 16383;
        int kt = r >> 12, nt = (r >> 9) & 7, lane = (r >> 3) & 63, j = r & 7;
        int k = kt * 32 + (lane >> 4) * 8 + j;
        int n = nt * 16 + (lane & 15);
        float w = (m == 0) ? flt_at(Wemb, fp32, (size_t)k * 128 + n)
                           : flt_at(Ws, fp32, (size_t)(m - 1) * 16384 + (size_t)k * 128 + n);
        __bf16 hi = (__bf16)w;
        Bhi[idx] = hi;
        Blo[idx] = (__bf16)(w - (float)hi);
    } else {
        int i = (b - 320) * 256 + tid;
        const void* src; float* dst; int off2;
        if (i < 128)       { src = bemb; dst = bemb_f; off2 = i; }
        else if (i < 640)  { src = bs;   dst = bs_f;   off2 = i - 128; }
        else if (i < 1152) { src = gam;  dst = gam_f;  off2 = i - 640; }
        else if (i < 1664) { src = bet;  dst = bet_f;  off2 = i - 1152; }
        else if (i < 2944) { src = Wm;   dst = Wm_f;   off2 = i - 1664; }
        else if (i < 2954) { src = bm;   dst = bm_f;   off2 = i - 2944; }
        else return;
        dst[off2] = flt_at(src, fp32, off2);
    }
}

// ---------------- single-pass edge convert + degree count ----------------
__global__ void k_edges(const void* ei, int* counts, int* srcs, int* dsts, const int* flags) {
    int e = blockIdx.x * 256 + threadIdx.x;
    if (e >= EE) return;
    int i64 = flags[1];
    int s = edge_at(ei, i64, e);
    int d = edge_at(ei, i64, (long long)EE + e);
    srcs[e] = s;
    dsts[e] = d;
    if ((unsigned)d < NN) atomicAdd(&counts[d], 1);
}

// exclusive scan of (counts+1) -> offsets; bsums = raw per-block totals
__global__ void k_scan1(const int* counts, int* offsets, int* bsums) {
    __shared__ int sc[256];
    int tid = threadIdx.x;
    int base = blockIdx.x * 1024 + tid * 4;
    int4 c = {0, 0, 0, 0};
    int4 d = {0, 0, 0, 0};
    if (base + 3 < NN) {
        c = *(const int4*)(counts + base);
        d.x = c.x + 1; d.y = c.y + 1; d.z = c.z + 1; d.w = c.w + 1;
    } else {
        if (base + 0 < NN) d.x = counts[base] + 1;
        if (base + 1 < NN) d.y = counts[base + 1] + 1;
        if (base + 2 < NN) d.z = counts[base + 2] + 1;
        if (base + 3 < NN) d.w = counts[base + 3] + 1;
    }
    int s = d.x + d.y + d.z + d.w;
    sc[tid] = s;
    __syncthreads();
    for (int off = 1; off < 256; off <<= 1) {
        int v = (tid >= off) ? sc[tid - off] : 0;
        __syncthreads();
        sc[tid] += v;
        __syncthreads();
    }
    int excl = sc[tid] - s;
    if (base < NN) {
        int4 o;
        o.x = excl; o.y = excl + d.x; o.z = o.y + d.y; o.w = o.z + d.z;
        *(int4*)(offsets + base) = o;
    }
    if (tid == 255) bsums[blockIdx.x] = sc[255];
}

// finalize offsets (inline 49-entry prefix of bsums) + zero cursor + dinv + place self-loops
__global__ void k_scan3(int* offsets, const int* bsums, const int* counts,
                        int* cursor, float* dinv, int* csr) {
    __shared__ int sadd;
    if (threadIdx.x == 0) {
        int a = 0;
        for (int i = 0; i < (int)blockIdx.x; ++i) a += bsums[i];
        sadd = a;
    }
    __syncthreads();
    int add = sadd;
    int base = blockIdx.x * 1024 + threadIdx.x * 4;
    if (base >= NN) return;
    int4 o = *(int4*)(offsets + base);
    o.x += add; o.y += add; o.z += add; o.w += add;
    *(int4*)(offsets + base) = o;
    int ov[4] = {o.x, o.y, o.z, o.w};
#pragma unroll
    for (int t = 0; t < 4; ++t) {
        int i = base + t;
        if (i < NN) {
            int c = counts[i];
            cursor[i] = 0;
            dinv[i] = rsqrtf((float)(c + 1));
            csr[ov[t] + c] = i;  // self-loop in last slot of segment
        }
    }
}

// ranged fill (keeps csr line writes XCD-local, matching round-robin dispatch)
__global__ void k_fill(const int* __restrict__ srcs, const int* __restrict__ dsts,
                       const int* __restrict__ offsets, int* cursor, int* csr) {
    int rlo = (blockIdx.x & 7) * 6250;
    for (int c = (int)(blockIdx.x >> 3); c < 3125; c += 391) {
        int e = c * 256 + threadIdx.x;
        int d = dsts[e];
        if ((unsigned)(d - rlo) < 6250u) {
            int s = srcs[e];
            if ((unsigned)s >= NN) s = d;
            int pos = offsets[d] + atomicAdd(&cursor[d], 1);
            csr[pos] = s;
        }
    }
}

// ---------------- BN affine helper ----------------
__device__ __forceinline__ void bn_affine(float sm, float sq, float g, float be,
                                          float& S, float& T) {
    float mu = sm * (1.f / NN);
    float var = fmaxf(sq * (1.f / NN) - mu * mu, 0.f);
    S = rsqrtf(var + BN_EPS) * g;
    T = be - mu * S;
}

__device__ __forceinline__ void sum_reps(const float* ST, int cb, float4& sm, float4& sq) {
    sm = make_float4(0.f, 0.f, 0.f, 0.f);
    sq = make_float4(0.f, 0.f, 0.f, 0.f);
#pragma unroll
    for (int rr = 0; rr < 8; ++rr) {
        float4 a = *(const float4*)(ST + rr * 256 + cb);
        float4 b = *(const float4*)(ST + rr * 256 + 128 + cb);
        sm.x += a.x; sm.y += a.y; sm.z += a.z; sm.w += a.w;
        sq.x += b.x; sq.y += b.y; sq.z += b.z; sq.w += b.w;
    }
}

// ---------------- shared MFMA core (64x128 A-tile, 128x128 B, hi/lo split) ----------------
__device__ __forceinline__ void mfma128(const __bf16 a_hi[][136], const __bf16 a_lo[][136],
                                        const __bf16* __restrict__ Bhi,
                                        const __bf16* __restrict__ Blo,
                                        int lane, int rw, int quad, int l15, f32x4* acc) {
#pragma unroll
    for (int nt = 0; nt < 8; ++nt) acc[nt] = (f32x4){0.f, 0.f, 0.f, 0.f};
#pragma unroll
    for (int kt = 0; kt < 4; ++kt) {
        int k0 = kt * 32 + quad * 8;
        bf16x8 ah = *(const bf16x8*)&a_hi[rw + l15][k0];
        bf16x8 al = *(const bf16x8*)&a_lo[rw + l15][k0];
#pragma unroll
        for (int nt = 0; nt < 8; ++nt) {
            size_t boff = (((size_t)(kt * 8 + nt) * 64 + lane) * 8);
            bf16x8 bh = *(const bf16x8*)(Bhi + boff);
            bf16x8 bl = *(const bf16x8*)(Blo + boff);
            acc[nt] = __builtin_amdgcn_mfma_f32_16x16x32_bf16(ah, bh, acc[nt], 0, 0, 0);
            acc[nt] = __builtin_amdgcn_mfma_f32_16x16x32_bf16(al, bh, acc[nt], 0, 0, 0);
            acc[nt] = __builtin_amdgcn_mfma_f32_16x16x32_bf16(ah, bl, acc[nt], 0, 0, 0);
        }
    }
}

__device__ __forceinline__ void stage_acc(float Cs[][132], const f32x4* acc,
                                          int rw, int quad, int l15) {
#pragma unroll
    for (int nt = 0; nt < 8; ++nt) {
        int col = nt * 16 + l15;
#pragma unroll
        for (int reg = 0; reg < 4; ++reg)
            Cs[rw + quad * 4 + reg][col] = acc[nt][reg];
    }
}

// ---------------- fused embedding + layer-0 linear ----------------
// h0 = input @ W_emb + b_emb  (fp32 -> C);  xb = bf16(h0 @ W_0)  (-> Cb)
__global__ __launch_bounds__(256) void k_gemm_emb(const void* __restrict__ Araw,
                                                  const __bf16* __restrict__ Bhi,
                                                  const __bf16* __restrict__ Blo,
                                                  const float* __restrict__ bias,
                                                  float* __restrict__ C,
                                                  unsigned short* __restrict__ Cb,
                                                  int M, const int* flags) {
    __shared__ __align__(16) char smem[2 * 64 * 136 * 2];
    __bf16 (*a_hi)[136] = (__bf16(*)[136])smem;
    __bf16 (*a_lo)[136] = (__bf16(*)[136])(smem + 64 * 136 * 2);
    float (*Cs)[132] = (float(*)[132])smem;
    int tid = threadIdx.x;
    int r0 = blockIdx.x * 64;
    int cq = tid & 31, rb = tid >> 5, cb4 = cq * 4;
    int afp32 = flags[0];
#pragma unroll
    for (int p = 0; p < 8; ++p) {
        int r = rb + p * 8;
        int gr = r0 + r;
        float f[4] = {0.f, 0.f, 0.f, 0.f};
        if (gr < M) {
            if (afp32) {
                float4 v = ((const float4*)Araw)[(size_t)gr * 32 + cq];
                f[0] = v.x; f[1] = v.y; f[2] = v.z; f[3] = v.w;
            } else {
                const __hip_bfloat16* ab = (const __hip_bfloat16*)Araw + (size_t)gr * 128 + cb4;
#pragma unroll
                for (int t = 0; t < 4; ++t) f[t] = (float)ab[t];
            }
        }
        union { __bf16 b[4]; ushort4 u; } ph, pl;
#pragma unroll
        for (int t = 0; t < 4; ++t) {
            __bf16 hi = (__bf16)f[t];
            ph.b[t] = hi;
            pl.b[t] = (__bf16)(f[t] - (float)hi);
        }
        *(ushort4*)&a_hi[r][cb4] = ph.u;
        *(ushort4*)&a_lo[r][cb4] = pl.u;
    }
    __syncthreads();
    int lane = tid & 63, wave = tid >> 6, quad = lane >> 4, l15 = lane & 15, rw = wave * 16;
    f32x4 acc[8];
    mfma128(a_hi, a_lo, Bhi, Blo, lane, rw, quad, l15, acc);     // W_emb
    __syncthreads();
    stage_acc(Cs, acc, rw, quad, l15);
    __syncthreads();
    // read h0 tile + bias into registers; write fp32 h0; keep for refeed
    int colc = (tid & 15) * 8;
    float4 b0v = *(const float4*)(bias + colc);
    float4 b1v = *(const float4*)(bias + colc + 4);
    float v[4][8];
#pragma unroll
    for (int p = 0; p < 4; ++p) {
        int row = (tid >> 4) + p * 16;
        *(float4*)&v[p][0] = *(const float4*)&Cs[row][colc];
        *(float4*)&v[p][4] = *(const float4*)&Cs[row][colc + 4];
        v[p][0] += b0v.x; v[p][1] += b0v.y; v[p][2] += b0v.z; v[p][3] += b0v.w;
        v[p][4] += b1v.x; v[p][5] += b1v.y; v[p][6] += b1v.z; v[p][7] += b1v.w;
        int gr = r0 + row;
        if (gr < M) {
            float* cr = C + (size_t)gr * 128 + colc;
            *(float4*)cr = *(float4*)&v[p][0];
            *(float4*)(cr + 4) = *(float4*)&v[p][4];
        }
    }
    __syncthreads();  // all Cs reads done before overwriting with A-frags
#pragma unroll
    for (int p = 0; p < 4; ++p) {
        int row = (tid >> 4) + p * 16;
        union { __bf16 b[8]; uint4 u; } ph, pl;
#pragma unroll
        for (int t = 0; t < 8; ++t) {
            float x = v[p][t];
            __bf16 hi = (__bf16)x;
            ph.b[t] = hi;
            pl.b[t] = (__bf16)(x - (float)hi);
        }
        *(uint4*)&a_hi[row][colc] = ph.u;
        *(uint4*)&a_lo[row][colc] = pl.u;
    }
    __syncthreads();
    mfma128(a_hi, a_lo, Bhi + 16384, Blo + 16384, lane, rw, quad, l15, acc);  // W_0
    __syncthreads();
    stage_acc(Cs, acc, rw, quad, l15);
    __syncthreads();
#pragma unroll
    for (int p = 0; p < 4; ++p) {
        int row = (tid >> 4) + p * 16;
        int gr = r0 + row;
        if (gr >= M) continue;
        float w[8];
        *(float4*)&w[0] = *(const float4*)&Cs[row][colc];
        *(float4*)&w[4] = *(const float4*)&Cs[row][colc + 4];
        union { unsigned short us[8]; uint4 u4; } pk;
#pragma unroll
        for (int t = 0; t < 8; ++t)
            pk.us[t] = __bfloat16_as_ushort(__float2bfloat16(w[t]));
        *(uint4*)(Cb + (size_t)gr * 128 + colc) = pk.u4;
    }
}

// ---------------- per-layer GEMM: A-row = hbuf + relu(BN(abuf)); writes h' and bf16 x ----------------
__global__ __launch_bounds__(256) void k_gemm_layer(const float* __restrict__ Ah,
                                                    const float* __restrict__ Aagg,
                                                    const float* __restrict__ ST,
                                                    const float* __restrict__ gamma,
                                                    const float* __restrict__ beta,
                                                    const __bf16* __restrict__ Bhi,
                                                    const __bf16* __restrict__ Blo,
                                                    unsigned short* __restrict__ Cb,
                                                    float* __restrict__ Hout, int M) {
    __shared__ __align__(16) char smem[2 * 64 * 136 * 2];
    __bf16 (*a_hi)[136] = (__bf16(*)[136])smem;
    __bf16 (*a_lo)[136] = (__bf16(*)[136])(smem + 64 * 136 * 2);
    float (*Cs)[132] = (float(*)[132])smem;
    int tid = threadIdx.x;
    int r0 = blockIdx.x * 64;
    int cq = tid & 31, rb = tid >> 5, cb4 = cq * 4;
    float4 S4, T4;
    {
        float4 sm, sq;
        sum_reps(ST, cb4, sm, sq);
        float4 g  = *(const float4*)(gamma + cb4);
        float4 be = *(const float4*)(beta + cb4);
        bn_affine(sm.x, sq.x, g.x, be.x, S4.x, T4.x);
        bn_affine(sm.y, sq.y, g.y, be.y, S4.y, T4.y);
        bn_affine(sm.z, sq.z, g.z, be.z, S4.z, T4.z);
        bn_affine(sm.w, sq.w, g.w, be.w, S4.w, T4.w);
    }
#pragma unroll
    for (int p = 0; p < 8; ++p) {
        int r = rb + p * 8;
        int gr = r0 + r;
        float f[4] = {0.f, 0.f, 0.f, 0.f};
        if (gr < M) {
            float4 v = *(const float4*)(Ah + (size_t)gr * 128 + cb4);
            float4 a = *(const float4*)(Aagg + (size_t)gr * 128 + cb4);
            v.x += fmaxf(fmaf(a.x, S4.x, T4.x), 0.f);
            v.y += fmaxf(fmaf(a.y, S4.y, T4.y), 0.f);
            v.z += fmaxf(fmaf(a.z, S4.z, T4.z), 0.f);
            v.w += fmaxf(fmaf(a.w, S4.w, T4.w), 0.f);
            *(float4*)(Hout + (size_t)gr * 128 + cb4) = v;
            f[0] = v.x; f[1] = v.y; f[2] = v.z; f[3] = v.w;
        }
        union { __bf16 b[4]; ushort4 u; } ph, pl;
#pragma unroll
        for (int t = 0; t < 4; ++t) {
            __bf16 hi = (__bf16)f[t];
            ph.b[t] = hi;
            pl.b[t] = (__bf16)(f[t] - (float)hi);
        }
        *(ushort4*)&a_hi[r][cb4] = ph.u;
        *(ushort4*)&a_lo[r][cb4] = pl.u;
    }
    __syncthreads();
    int lane = tid & 63, wave = tid >> 6, quad = lane >> 4, l15 = lane & 15, rw = wave * 16;
    f32x4 acc[8];
    mfma128(a_hi, a_lo, Bhi, Blo, lane, rw, quad, l15, acc);
    __syncthreads();
    stage_acc(Cs, acc, rw, quad, l15);
    __syncthreads();
    int colc = (tid & 15) * 8;
#pragma unroll
    for (int p = 0; p < 4; ++p) {
        int row = (tid >> 4) + p * 16;
        int gr = r0 + row;
        if (gr >= M) continue;
        float w[8];
        *(float4*)&w[0] = *(const float4*)&Cs[row][colc];
        *(float4*)&w[4] = *(const float4*)&Cs[row][colc + 4];
        union { unsigned short us[8]; uint4 u4; } pk;
#pragma unroll
        for (int t = 0; t < 8; ++t)
            pk.us[t] = __bfloat16_as_ushort(__float2bfloat16(w[t]));
        *(uint4*)(Cb + (size_t)gr * 128 + colc) = pk.u4;
    }
}

// ---------------- aggregation with fused BN statistics ----------------
// 16 nodes/block (wave-per-node, 4 sequential). Register-accumulated column sums/sumsq
// -> per-block LDS reduce -> one atomicAdd per thread into the layer's 8-replica stats.
__global__ __launch_bounds__(256) void k_agg(const unsigned int* __restrict__ xb,
                                             const int* __restrict__ csr,
                                             const int* __restrict__ offsets,
                                             const int* __restrict__ counts,
                                             const float* __restrict__ dinv,
                                             const float* __restrict__ bias,
                                             float* __restrict__ out,
                                             float* __restrict__ stats) {
    int tid = threadIdx.x;
    int wave = tid >> 6, lane = tid & 63;
    int l15 = lane & 15, quarter = lane >> 4;
    int col = l15 * 8;
    float4 b0 = *(const float4*)(bias + col);
    float4 b1 = *(const float4*)(bias + col + 4);
    float ssm[8] = {0.f, 0.f, 0.f, 0.f, 0.f, 0.f, 0.f, 0.f};
    float ssq[8] = {0.f, 0.f, 0.f, 0.f, 0.f, 0.f, 0.f, 0.f};
#pragma unroll 1
    for (int p = 0; p < 4; ++p) {
        int node = blockIdx.x * 16 + p * 4 + wave;
        int start = offsets[node];
        int cnt = counts[node] + 1;  // + self-loop
        float dn = dinv[node];
        float accA[8] = {0.f, 0.f, 0.f, 0.f, 0.f, 0.f, 0.f, 0.f};
        float accB[8] = {0.f, 0.f, 0.f, 0.f, 0.f, 0.f, 0.f, 0.f};
        for (int base = 0; base < cnt; base += 64) {
            int sidx = 0;
            float wl = 0.f;
            if (base + lane < cnt) {
                sidx = csr[start + base + lane];
                wl = dinv[sidx] * dn;
            }
            int m = min(64, cnt - base);
            int j = 0;
            for (; j + 4 < m; j += 8) {
                int e0 = j + quarter;
                int e1 = j + 4 + quarter;
                int s0 = __shfl(sidx, e0);
                float w0 = __shfl(wl, e0);
                int s1 = __shfl(sidx, e1);
                float w1 = __shfl(wl, e1);
                uint4 u0 = *((const uint4*)(xb + (size_t)s0 * 64) + l15);
                uint4 u1 = *((const uint4*)(xb + (size_t)s1 * 64) + l15);
                accA[0] = fmaf(bf_lo(u0.x), w0, accA[0]);
                accA[1] = fmaf(bf_hi(u0.x), w0, accA[1]);
                accA[2] = fmaf(bf_lo(u0.y), w0, accA[2]);
                accA[3] = fmaf(bf_hi(u0.y), w0, accA[3]);
                accA[4] = fmaf(bf_lo(u0.z), w0, accA[4]);
                accA[5] = fmaf(bf_hi(u0.z), w0, accA[5]);
                accA[6] = fmaf(bf_lo(u0.w), w0, accA[6]);
                accA[7] = fmaf(bf_hi(u0.w), w0, accA[7]);
                accB[0] = fmaf(bf_lo(u1.x), w1, accB[0]);
                accB[1] = fmaf(bf_hi(u1.x), w1, accB[1]);
                accB[2] = fmaf(bf_lo(u1.y), w1, accB[2]);
                accB[3] = fmaf(bf_hi(u1.y), w1, accB[3]);
                accB[4] = fmaf(bf_lo(u1.z), w1, accB[4]);
                accB[5] = fmaf(bf_hi(u1.z), w1, accB[5]);
                accB[6] = fmaf(bf_lo(u1.w), w1, accB[6]);
                accB[7] = fmaf(bf_hi(u1.w), w1, accB[7]);
            }
            if (j < m) {
                int e0 = j + quarter;
                int s0 = __shfl(sidx, e0);
                float w0 = __shfl(wl, e0);
                uint4 u0 = *((const uint4*)(xb + (size_t)s0 * 64) + l15);
                accA[0] = fmaf(bf_lo(u0.x), w0, accA[0]);
                accA[1] = fmaf(bf_hi(u0.x), w0, accA[1]);
                accA[2] = fmaf(bf_lo(u0.y), w0, accA[2]);
                accA[3] = fmaf(bf_hi(u0.y), w0, accA[3]);
                accA[4] = fmaf(bf_lo(u0.z), w0, accA[4]);
                accA[5] = fmaf(bf_hi(u0.z), w0, accA[5]);
                accA[6] = fmaf(bf_lo(u0.w), w0, accA[6]);
                accA[7] = fmaf(bf_hi(u0.w), w0, accA[7]);
            }
        }
#pragma unroll
        for (int k = 0; k < 8; ++k) {
            float a = accA[k] + accB[k];
            a += __shfl_xor(a, 16);
            a += __shfl_xor(a, 32);
            accA[k] = a;
        }
        if (quarter == 0) {
            float o[8];
            o[0] = accA[0] + b0.x; o[1] = accA[1] + b0.y;
            o[2] = accA[2] + b0.z; o[3] = accA[3] + b0.w;
            o[4] = accA[4] + b1.x; o[5] = accA[5] + b1.y;
            o[6] = accA[6] + b1.z; o[7] = accA[7] + b1.w;
            float* orow = out + (size_t)node * 128 + col;
            *(float4*)orow = *(float4*)&o[0];
            *(float4*)(orow + 4) = *(float4*)&o[4];
#pragma unroll
            for (int k = 0; k < 8; ++k) {
                ssm[k] += o[k];
                ssq[k] = fmaf(o[k], o[k], ssq[k]);
            }
        }
    }
    __shared__ float red[4][256];
    if (quarter == 0) {
#pragma unroll
        for (int k = 0; k < 8; ++k) {
            red[wave][col + k] = ssm[k];
            red[wave][128 + col + k] = ssq[k];
        }
    }
    __syncthreads();
    float v = red[0][tid] + red[1][tid] + red[2][tid] + red[3][tid];
    atomicAdd(&stats[(blockIdx.x & 7) * 256 + tid], v);
}

// ---------------- fused final BN + MLP ----------------
__global__ __launch_bounds__(256) void k_mlp_fused(const float* __restrict__ h,
                                                   const float* __restrict__ agg,
                                                   const float* __restrict__ ST,
                                                   const float* __restrict__ gamma,
                                                   const float* __restrict__ beta,
                                                   const float* __restrict__ Wm,
                                                   const float* __restrict__ bm,
                                                   void* __restrict__ out,
                                                   const int* __restrict__ flags) {
    __shared__ float Wt[10][132];
    int tid = threadIdx.x;
    for (int i = tid; i < 1280; i += 256) {
        int cls = i >> 7, k = i & 127;
        Wt[cls][k] = Wm[k * 10 + cls];
    }
    __syncthreads();
    int wave = tid >> 6, lane = tid & 63;
    int nl = lane >> 4, c = lane & 15;
    int node = blockIdx.x * 16 + wave * 4 + nl;
    size_t rowo = (size_t)node * 128 + c * 8;
    float4 h0 = *(const float4*)(h + rowo);
    float4 h1 = *(const float4*)(h + rowo + 4);
    float4 a0 = *(const float4*)(agg + rowo);
    float4 a1 = *(const float4*)(agg + rowo + 4);
    float S[8], T[8];
#pragma unroll
    for (int q = 0; q < 2; ++q) {
        float4 sm, sq;
        sum_reps(ST, c * 8 + q * 4, sm, sq);
        float4 g  = *(const float4*)(gamma + c * 8 + q * 4);
        float4 be = *(const float4*)(beta + c * 8 + q * 4);
        bn_affine(sm.x, sq.x, g.x, be.x, S[q * 4 + 0], T[q * 4 + 0]);
        bn_affine(sm.y, sq.y, g.y, be.y, S[q * 4 + 1], T[q * 4 + 1]);
        bn_affine(sm.z, sq.z, g.z, be.z, S[q * 4 + 2], T[q * 4 + 2]);
        bn_affine(sm.w, sq.w, g.w, be.w, S[q * 4 + 3], T[q * 4 + 3]);
    }
    float hv[8];
    hv[0] = h0.x + fmaxf(fmaf(a0.x, S[0], T[0]), 0.f);
    hv[1] = h0.y + fmaxf(fmaf(a0.y, S[1], T[1]), 0.f);
    hv[2] = h0.z + fmaxf(fmaf(a0.z, S[2], T[2]), 0.f);
    hv[3] = h0.w + fmaxf(fmaf(a0.w, S[3], T[3]), 0.f);
    hv[4] = h1.x + fmaxf(fmaf(a1.x, S[4], T[4]), 0.f);
    hv[5] = h1.y + fmaxf(fmaf(a1.y, S[5], T[5]), 0.f);
    hv[6] = h1.z + fmaxf(fmaf(a1.z, S[6], T[6]), 0.f);
    hv[7] = h1.w + fmaxf(fmaf(a1.w, S[7], T[7]), 0.f);
    float p[10];
#pragma unroll
    for (int cls = 0; cls < 10; ++cls) {
        float4 w0 = *(const float4*)&Wt[cls][c * 8];
        float4 w1 = *(const float4*)&Wt[cls][c * 8 + 4];
        float sacc = fmaf(hv[0], w0.x, fmaf(hv[1], w0.y, fmaf(hv[2], w0.z, hv[3] * w0.w)));
        sacc = fmaf(hv[4], w1.x, fmaf(hv[5], w1.y, fmaf(hv[6], w1.z, fmaf(hv[7], w1.w, sacc))));
        p[cls] = sacc;
    }
#pragma unroll
    for (int m = 1; m < 16; m <<= 1)
#pragma unroll
        for (int cls = 0; cls < 10; ++cls)
            p[cls] += __shfl_xor(p[cls], m);
    if (c == 0) {
        if (flags[0]) {
            float* o = (float*)out;
            for (int cls = 0; cls < 10; ++cls) o[node * 10 + cls] = p[cls] + bm[cls];
        } else {
            __hip_bfloat16* o = (__hip_bfloat16*)out;
            for (int cls = 0; cls < 10; ++cls)
                o[node * 10 + cls] = __float2bfloat16(p[cls] + bm[cls]);
        }
    }
}

// ---------------- orchestration ----------------

extern "C" void kernel_launch(void* const* d_in, const int* in_sizes, int n_in,
                              void* d_out, int out_size, void* d_ws, size_t ws_size,
                              hipStream_t stream) {
    const void* h_in = d_in[0];
    const void* ei   = d_in[1];
    const void* Wemb = d_in[3];
    const void* bemb = d_in[4];
    const void* Ws   = d_in[5];
    const void* bs   = d_in[6];
    const void* gam  = d_in[7];
    const void* bet  = d_in[8];
    const void* Wm   = d_in[9];
    const void* bm   = d_in[10];

    char* ws = (char*)d_ws;
    size_t off = 0;
    auto alloc = [&](size_t bytes) -> void* {
        void* p = ws + off;
        off = (off + bytes + 255) & ~(size_t)255;
        return p;
    };
    float* hbuf    = (float*)alloc((size_t)NN * 128 * 4);
    float* abuf    = (float*)alloc((size_t)NN * 128 * 4);
    unsigned int* xb = (unsigned int*)alloc((size_t)NN * 64 * 4);   // bf16 x, 256 B/row
    int* counts    = (int*)alloc((size_t)(NN + 1024) * 4);
    int* offsets   = (int*)alloc((size_t)(NN + 1024) * 4);
    int* cursor    = (int*)alloc((size_t)NN * 4);
    int* bsums     = (int*)alloc(64 * 4);
    float* dinv    = (float*)alloc((size_t)NN * 4);
    float* stats8  = (float*)alloc((size_t)4 * 8 * 256 * 4);        // per-layer 8-replica stats
    int* csr       = (int*)alloc((size_t)(EE + NN + 64) * 4);
    int* srcs      = (int*)alloc((size_t)EE * 4);
    int* dsts      = (int*)alloc((size_t)EE * 4);
    int* flags     = (int*)alloc(64);
    float* bemb_f  = (float*)alloc(128 * 4);
    float* bs_f    = (float*)alloc(512 * 4);
    float* gam_f   = (float*)alloc(512 * 4);
    float* bet_f   = (float*)alloc(512 * 4);
    float* Wm_f    = (float*)alloc(1280 * 4);
    float* bm_f    = (float*)alloc(16 * 4);
    __bf16* Bhi    = (__bf16*)alloc((size_t)5 * 16384 * 2);
    __bf16* Blo    = (__bf16*)alloc((size_t)5 * 16384 * 2);

    k_setup<<<348, 256, 0, stream>>>(h_in, ei, Wemb, Ws, bemb, bs, gam, bet, Wm, bm,
                                     bemb_f, bs_f, gam_f, bet_f, Wm_f, bm_f,
                                     Bhi, Blo, counts, stats8, flags);
    k_edges<<<3125, 256, 0, stream>>>(ei, counts, srcs, dsts, flags);
    int nb = (NN + 1023) / 1024;  // 49
    k_scan1<<<nb, 256, 0, stream>>>(counts, offsets, bsums);
    k_scan3<<<nb, 256, 0, stream>>>(offsets, bsums, counts, cursor, dinv, csr);
    k_fill<<<3128, 256, 0, stream>>>(srcs, dsts, offsets, cursor, csr);

    int gblocks = (NN + 63) / 64;  // 782
    // fused: hbuf = input @ W_emb + b_emb; xb = bf16(hbuf @ W_0)
    k_gemm_emb<<<gblocks, 256, 0, stream>>>(h_in, Bhi, Blo, bemb_f, hbuf,
                                            (unsigned short*)xb, NN, flags);

    for (int l = 0; l < NL; ++l) {
        k_agg<<<NN / 16, 256, 0, stream>>>(xb, csr, offsets, counts, dinv,
                                           bs_f + l * 128, abuf, stats8 + (size_t)l * 2048);
        if (l < 3) {
            // h_{l+1} = h_l + relu(BN_l(abuf)); xb = bf16(h_{l+1} @ W_{l+1})
            k_gemm_layer<<<gblocks, 256, 0, stream>>>(hbuf, abuf, stats8 + (size_t)l * 2048,
                                                      gam_f + l * 128, bet_f + l * 128,
                                                      Bhi + (size_t)(2 + l) * 16384,
                                                      Blo + (size_t)(2 + l) * 16384,
                                                      (unsigned short*)xb, hbuf, NN);
        }
    }
    // final: h4 = h3 + relu(BN_3(abuf)); out = h4 @ W_mlp + b_mlp
    k_mlp_fused<<<NN / 16, 256, 0, stream>>>(hbuf, abuf, stats8 + (size_t)3 * 2048,
                                             gam_f + 3 * 128, bet_f + 3 * 128,
                                             Wm_f, bm_f, d_out, flags);
}